// Round 9
// baseline (158.737 us; speedup 1.0000x reference)
//
#include <hip/hip_runtime.h>
#include <cstdint>
#include <cstddef>

typedef unsigned short u16;
typedef __attribute__((ext_vector_type(8))) short short8;
typedef __attribute__((ext_vector_type(8))) u16 ushort8;
typedef __attribute__((ext_vector_type(4))) float float4_t;

#define BB 8
#define NN 8192
#define DD 64
#define TILE_SHORTS 8192     // 128 points * 64 k (bf16)
#define LDS_STRIDE 68        // 64 floats + 4 pad (bank spread)

__device__ inline u16 f32_to_bf16(float f) {
  unsigned u = __float_as_uint(f);
  u += 0x7FFFu + ((u >> 16) & 1u);   // RNE
  return (u16)(u >> 16);
}

__device__ inline unsigned enc_ord(float f) {
  unsigned u = __float_as_uint(f);
  return (u & 0x80000000u) ? ~u : (u | 0x80000000u);
}
__device__ inline float dec_ord(unsigned u) {
  return __uint_as_float((u & 0x80000000u) ? (u & 0x7fffffffu) : ~u);
}

// ---------------------------------------------------------------------------
// K1: one block = one 128x64 tile. Coalesced read-once -> LDS -> swizzled
// bf16 tile (MFMA fragment chunk order) + 0.5*|row|^2.  [verified R6/R7]
// rowmax_u zero-inited ALWAYS (rows use end-of-kernel atomics both paths);
// colmax_u only in the fallback path.
// ---------------------------------------------------------------------------
__global__ __launch_bounds__(256) void pre_kernel(
    const float* __restrict__ x, const float* __restrict__ y,
    u16* __restrict__ xs, u16* __restrict__ ys,
    float* __restrict__ x2h, float* __restrict__ y2h,
    unsigned* __restrict__ rowmax_u, unsigned* __restrict__ colmax_u,
    float* __restrict__ out, const int use_part)
{
  __shared__ float stage[128 * LDS_STRIDE];   // 34 KB

  const int bid = blockIdx.x;          // 1024: 0..511 -> x, 512..1023 -> y
  const int tid = threadIdx.x;

  if (bid >= 256 && bid < 512) rowmax_u[((bid - 256) << 8) | tid] = 0u;
  if (!use_part && bid < 256)  colmax_u[(bid << 8) | tid] = 0u;
  if (bid == 0 && tid == 0) out[0] = 0.f;

  const bool isY = bid >= 512;
  const int t = bid & 511;             // tile id = b*64 + nt
  const float* src = (isY ? y : x) + (size_t)t * (128 * DD);
  u16* dst = (isY ? ys : xs) + (size_t)t * TILE_SHORTS;
  float* s2 = (isY ? y2h : x2h) + t * 128;

#pragma unroll
  for (int c = 0; c < 8; ++c) {
    const int idx = c * 256 + tid;     // float4 index within tile (0..2047)
    float4 f = ((const float4*)src)[idx];
    const int r = idx >> 4, kc = idx & 15;
    *(float4*)&stage[r * LDS_STRIDE + kc * 4] = f;
  }
  __syncthreads();

  {
    const int r = tid >> 1, half = tid & 1;
    const float* rp = &stage[r * LDS_STRIDE + half * 32];
    float ss = 0.f;
#pragma unroll
    for (int k = 0; k < 8; ++k) {
      float4 f = *(const float4*)&rp[k * 4];
      ss += f.x*f.x + f.y*f.y + f.z*f.z + f.w*f.w;
    }
    ss += __shfl_xor(ss, 1);
    if (half == 0) s2[r] = 0.5f * ss;
  }

  {
    const int w = tid >> 6, lane = tid & 63;
    const int qq = lane >> 4, rl = lane & 15;
#pragma unroll
    for (int u = 0; u < 4; ++u) {
      const int chunk = w * 4 + u;
      const int I = chunk >> 1, s = chunk & 1;
      const float* rp = &stage[(I*16 + rl) * LDS_STRIDE + s*32 + qq*8];
      ushort8 o;
#pragma unroll
      for (int j = 0; j < 8; ++j) o[j] = f32_to_bf16(rp[j]);
      *(ushort8*)(dst + chunk*512 + lane*8) = o;
    }
  }
}

// ---------------------------------------------------------------------------
// K2: main — R17.  R16 (75us, best): fire-and-forget ds_max_u32 confirmed
// the cross-lane-wait theory (MfmaUtil 31->39). Remaining per-wave critical
// path: reduction READS THE ACC JUST COMPUTED -> per step the wave pays
// 8 MFMA issue (~155 cyc, in-order) + last-MFMA writeback (~40-60) + ~120
// dependent VALU = ~315 cyc, MFMA duty ~50%.
// R17 = R16 verbatim + 1-STEP-DELAYED ACC PING-PONG (T15 mechanism where a
// real serialization exists): step s MFMAs into accA/accB (alternating,
// static names — rule #20), and reduces the PREVIOUS step's acc. The
// reduction has zero dep on the in-flight MFMAs, so the compiler
// interleaves its VALU into the idle issue slots between MFMA issues ->
// per-wave step ~ max(155, VALU) ~ 170 cyc.
// First-step dummy reduce is a provable no-op: accB init -3e38 (enc_ord
// below every real slot value — every slot later receives all 128 real
// rows), y23 init 0 (so -3e38-0 stays -3e38 in rowmax), moff clamped 0.
// Epilogue reduces the final acc (mt15/jj3, y23 still live). y2X overwrite
// hazard checked: reduce(s-1) in step s; y[(s-1)&3] overwritten in s+1.
// +16 VGPR vs R16's measured 72 -> ~90-105, (256,3), no spill expected
// (tripwire: WRITE_SIZE 17.4 MB). (256,4) ban stands.
// ---------------------------------------------------------------------------
__global__ __launch_bounds__(256, 3) void main_kernel(
    const u16* __restrict__ xs, const u16* __restrict__ ys,
    const float* __restrict__ x2h, const float* __restrict__ y2h,
    float* __restrict__ colpart,
    unsigned* __restrict__ rowmax_u, unsigned* __restrict__ colmax_u,
    const int use_part)
{
  __shared__ unsigned colbufu[2048];   // 8 KB: [mt*128 + col], enc_ord
  __shared__ float rowbuf[2][128];     // [wc][row]

  const int bid = blockIdx.x;            // 2048
  const int b   = bid & 7;               // XCD-affine
  const int nt  = (bid >> 3) & 63;
  const int h   = bid >> 9;              // 0..3 column quarter
  const int tid = threadIdx.x;
  const int w = tid >> 6, lane = tid & 63;
  const int wr = w >> 1, wc = w & 1;     // row-half / col-half owner
  const int l15 = lane & 15, q = lane >> 4;
  const int n0 = nt << 7;
  const int mt_start = h << 4;           // 16 col-tiles per block

  // colbufu init: 0u is below enc_ord of every finite float
#pragma unroll
  for (int k = 0; k < 8; ++k) colbufu[k * 256 + tid] = 0u;

  // ---- A fragments: this wave's 64 rows, both K-halves ----
  const u16* xs_tile = xs + (size_t)((b << 6) | nt) * TILE_SHORTS;
  short8 afr[4][2];
#pragma unroll
  for (int i = 0; i < 4; ++i)
#pragma unroll
    for (int s = 0; s < 2; ++s)
      afr[i][s] = *(const short8*)(xs_tile + ((wr*4 + i)*2 + s)*512 + lane*8);

  // ---- C-init quads: -x2/2 per row (fp32 exact) ----
  float4_t negx2[4];
  const float* x2b = x2h + b*NN + n0 + wr*64;
#pragma unroll
  for (int i = 0; i < 4; ++i) {
    float4_t v = *(const float4_t*)(x2b + i*16 + q*4);
    negx2[i] = {-v[0], -v[1], -v[2], -v[3]};
  }

  float rowmax[4][4];
#pragma unroll
  for (int i = 0; i < 4; ++i)
#pragma unroll
    for (int r = 0; r < 4; ++r) rowmax[i][r] = -3.0e38f;

  // ---- pointer-bumped streams; imm offsets cover the chunk loads ----
  const u16*  pB = ys + (size_t)((b << 6) + mt_start) * TILE_SHORTS
                   + wc*4096 + lane*8;
  const float* pY = y2h + b*NN + mt_start*128 + wc*64 + l15;

  // ---- depth-2 pipeline, 4 static B buffers + acc ping-pong ----
  short8 b0lo, b0hi, b1lo, b1hi, b2lo, b2hi, b3lo, b3hi;
  float  y20, y21, y22, y23;
  b0lo = *(const short8*)(pB);
  b0hi = *(const short8*)(pB + 512);
  y20  = pY[0];
  b1lo = *(const short8*)(pB + 1024);
  b1hi = *(const short8*)(pB + 1536);
  y21  = pY[16];
  y23  = 0.f;                            // dummy first reduce reads it

  float4_t accA[4], accB[4];
#pragma unroll
  for (int i = 0; i < 4; ++i)
    accB[i] = {-3.0e38f, -3.0e38f, -3.0e38f, -3.0e38f};  // dummy: no-op reduce

  __syncthreads();                       // colbufu init visible to all waves

  int moff = 0;
  for (int mt = 0; mt < 16; ++mt) {
    const int mprev = (moff == 0) ? 0 : (moff - 128);
    // STEP(JJ): prefetch step JJ+2; MFMA step JJ into AC; reduce PREVIOUS
    // step's acc AP (independent of the in-flight MFMAs).
#define CHAM_STEP(JJ, NOFF, NY, C0, C1, YC, N0, N1, YN, AC, AP, PJJ, PYC, PMOFF) \
    {                                                                         \
      N0 = *(const short8*)(pB + (NOFF));                                     \
      N1 = *(const short8*)(pB + (NOFF) + 512);                               \
      YN = pY[(NY)];                                                          \
      /* acc = xy - x2/2 (C carries exact fp32 -x2/2) */                      \
      __builtin_amdgcn_s_setprio(1);                                          \
      AC[0] = __builtin_amdgcn_mfma_f32_16x16x32_bf16(afr[0][0], C0, negx2[0], 0, 0, 0); \
      AC[1] = __builtin_amdgcn_mfma_f32_16x16x32_bf16(afr[1][0], C0, negx2[1], 0, 0, 0); \
      AC[2] = __builtin_amdgcn_mfma_f32_16x16x32_bf16(afr[2][0], C0, negx2[2], 0, 0, 0); \
      AC[3] = __builtin_amdgcn_mfma_f32_16x16x32_bf16(afr[3][0], C0, negx2[3], 0, 0, 0); \
      AC[0] = __builtin_amdgcn_mfma_f32_16x16x32_bf16(afr[0][1], C1, AC[0], 0, 0, 0);    \
      AC[1] = __builtin_amdgcn_mfma_f32_16x16x32_bf16(afr[1][1], C1, AC[1], 0, 0, 0);    \
      AC[2] = __builtin_amdgcn_mfma_f32_16x16x32_bf16(afr[2][1], C1, AC[2], 0, 0, 0);    \
      AC[3] = __builtin_amdgcn_mfma_f32_16x16x32_bf16(afr[3][1], C1, AC[3], 0, 0, 0);    \
      __builtin_amdgcn_s_setprio(0);                                          \
      /* reduce previous acc: in-lane 16-row max tree + fire-and-forget    */ \
      /* LDS ds_max_u32 (result unused -> no wave-visible wait)            */ \
      float t0 = fmaxf(fmaxf(AP[0][0], AP[0][1]), AP[0][2]);                  \
      float t1 = fmaxf(fmaxf(AP[0][3], AP[1][0]), AP[1][1]);                  \
      float t2 = fmaxf(fmaxf(AP[1][2], AP[1][3]), AP[2][0]);                  \
      float t3 = fmaxf(fmaxf(AP[2][1], AP[2][2]), AP[2][3]);                  \
      float t4 = fmaxf(fmaxf(AP[3][0], AP[3][1]), AP[3][2]);                  \
      float u0 = fmaxf(fmaxf(t0, t1), t2);                                    \
      float u1 = fmaxf(fmaxf(t3, t4), AP[3][3]);                              \
      float cm = fmaxf(u0, u1);                                               \
      atomicMax(&colbufu[(PMOFF) + wc*64 + (PJJ)*16 + l15], enc_ord(cm));     \
      /* row side: rowmax = max(AP - y2/2) = -min(d^2)/2 */                   \
      {                                                                       \
        const float y2j = (PYC);                                              \
        for (int i_ = 0; i_ < 4; ++i_)                                        \
          for (int r_ = 0; r_ < 4; ++r_)                                      \
            rowmax[i_][r_] = fmaxf(rowmax[i_][r_], AP[i_][r_] - y2j);         \
      }                                                                       \
    }
    // step jj: consume b[jj], load b[(jj+2)&3]; reduce step jj-1's acc
    CHAM_STEP(0, 2048,              32,  b0lo, b0hi, y20, b2lo, b2hi, y22,
              accA, accB, 3, y23, mprev)
    CHAM_STEP(1, 3072,              48,  b1lo, b1hi, y21, b3lo, b3hi, y23,
              accB, accA, 0, y20, moff)
    CHAM_STEP(2, TILE_SHORTS,       128, b2lo, b2hi, y22, b0lo, b0hi, y20,
              accA, accB, 1, y21, moff)
    CHAM_STEP(3, TILE_SHORTS+1024,  144, b3lo, b3hi, y23, b1lo, b1hi, y21,
              accB, accA, 2, y22, moff)
#undef CHAM_STEP
    pB += TILE_SHORTS;
    pY += 128;
    moff += 128;
  }

  // ---- epilogue: reduce the final step's acc (mt15, jj3, y23 live) ----
  {
    const int pmoff = moff - 128;        // 1920
    float t0 = fmaxf(fmaxf(accB[0][0], accB[0][1]), accB[0][2]);
    float t1 = fmaxf(fmaxf(accB[0][3], accB[1][0]), accB[1][1]);
    float t2 = fmaxf(fmaxf(accB[1][2], accB[1][3]), accB[2][0]);
    float t3 = fmaxf(fmaxf(accB[2][1], accB[2][2]), accB[2][3]);
    float t4 = fmaxf(fmaxf(accB[3][0], accB[3][1]), accB[3][2]);
    float u0 = fmaxf(fmaxf(t0, t1), t2);
    float u1 = fmaxf(fmaxf(t3, t4), accB[3][3]);
    float cm = fmaxf(u0, u1);
    atomicMax(&colbufu[pmoff + wc*64 + 3*16 + l15], enc_ord(cm));
    const float y2j = y23;
#pragma unroll
    for (int i_ = 0; i_ < 4; ++i_)
#pragma unroll
      for (int r_ = 0; r_ < 4; ++r_)
        rowmax[i_][r_] = fmaxf(rowmax[i_][r_], accB[i_][r_] - y2j);
  }

  // ---- row side finalize: shfl over cols (l15), cross-wc via LDS ----
#pragma unroll
  for (int i = 0; i < 4; ++i)
#pragma unroll
    for (int r = 0; r < 4; ++r) {
      float v = rowmax[i][r];
      v = fmaxf(v, __shfl_xor(v, 1));
      v = fmaxf(v, __shfl_xor(v, 2));
      v = fmaxf(v, __shfl_xor(v, 4));
      v = fmaxf(v, __shfl_xor(v, 8));
      rowmax[i][r] = v;
    }
  if (l15 == 0) {
#pragma unroll
    for (int i = 0; i < 4; ++i)
#pragma unroll
      for (int r = 0; r < 4; ++r)
        rowbuf[wc][wr*64 + i*16 + q*4 + r] = rowmax[i][r];
  }
  __syncthreads();   // colbufu atomics + rowbuf complete (lgkmcnt-drained)

  // rows: one end-of-kernel device atomic per row (both paths)
  if (tid < 128) {
    float v = fmaxf(rowbuf[0][tid], rowbuf[1][tid]);     // -min(d^2)/2
    atomicMax(&rowmax_u[b*NN + n0 + tid], enc_ord(v));
  }

  // ---- col drain: decode single plane; 8 KB coalesced (partial path) ----
  {
    float*    colp = colpart + (size_t)((b << 6) | nt) * NN + (h << 11);
    unsigned* colu = colmax_u + b*NN + (h << 11);
#pragma unroll
    for (int k = 0; k < 8; ++k) {
      const int t = k * 256 + tid;
      const unsigned e = colbufu[t];
      if (use_part) colp[t] = dec_ord(e);
      else          atomicMax(&colu[t], e);
    }
  }
}

// ---------------------------------------------------------------------------
// K3: col combine over 64 nt + sqrt; rows from rowmax_u (always atomic) +
// sqrt; block sum; atomicAdd scaled result into out.
// ---------------------------------------------------------------------------
__global__ __launch_bounds__(256) void reduce_kernel(
    const float* __restrict__ colpart,
    const unsigned* __restrict__ rowmax_u, const unsigned* __restrict__ colmax_u,
    const float* __restrict__ y2h, float* __restrict__ out,
    const int use_part)
{
  const int bid = blockIdx.x;          // 256
  const int tid = threadIdx.x;
  const int g = bid*256 + tid;         // 0..65535
  const int b = g >> 13, m = g & (NN - 1);

  float vc;
  if (use_part) {
    vc = -3.0e38f;
#pragma unroll 8
    for (int nt = 0; nt < 64; ++nt)
      vc = fmaxf(vc, colpart[(size_t)((b << 6) | nt) * NN + m]);
  } else {
    vc = dec_ord(colmax_u[g]);
  }
  float vr = dec_ord(rowmax_u[g]);
  float s = sqrtf(fmaxf(2.f*(y2h[g] - vc), 0.f))   // nearest-x for this y
          + sqrtf(fmaxf(-2.f*vr, 0.f));            // nearest-y for this x

#pragma unroll
  for (int d = 1; d < 64; d <<= 1) s += __shfl_xor(s, d);
  __shared__ float wsum[4];
  if ((tid & 63) == 0) wsum[tid >> 6] = s;
  __syncthreads();
  if (tid == 0)
    atomicAdd(out, (wsum[0] + wsum[1] + wsum[2] + wsum[3]) * (1.0f / 65536.0f));
}

// ---------------------------------------------------------------------------
extern "C" void kernel_launch(void* const* d_in, const int* in_sizes, int n_in,
                              void* d_out, int out_size, void* d_ws, size_t ws_size,
                              hipStream_t stream) {
  const float* x = (const float*)d_in[0];
  const float* y = (const float*)d_in[1];
  float* out = (float*)d_out;

  char* p = (char*)d_ws;
  u16* xs = (u16*)p;            p += (size_t)512 * 16384;   // 8 MiB
  u16* ys = (u16*)p;            p += (size_t)512 * 16384;   // 8 MiB
  float* x2h = (float*)p;       p += (size_t)65536 * 4;
  float* y2h = (float*)p;       p += (size_t)65536 * 4;
  char* tail = p;
  // partial path: colpart 16 MiB, then rowmax_u 256 KiB.
  // need = 16.5 + 16 + 0.25 = 32.75 MiB  (< R0-proven 33.0 MiB)
  float* colpart = (float*)tail;
  // atomic fallback: colmax_u at tail, rowmax_u right after (512 KiB total)
  unsigned* colmax_u = (unsigned*)tail;
  const size_t need_part = (size_t)(tail - (char*)d_ws) +
                           (size_t)512 * 8192 * 4 + (size_t)65536 * 4;
  const int use_part = (ws_size >= need_part) ? 1 : 0;
  unsigned* rowmax_u = use_part
      ? (unsigned*)(tail + (size_t)512 * 8192 * 4)
      : (unsigned*)(tail + (size_t)65536 * 4);

  pre_kernel<<<dim3(1024), dim3(256), 0, stream>>>(x, y, xs, ys, x2h, y2h,
                                                   rowmax_u, colmax_u, out,
                                                   use_part);
  main_kernel<<<dim3(2048), dim3(256), 0, stream>>>(xs, ys, x2h, y2h,
                                                    colpart,
                                                    rowmax_u, colmax_u,
                                                    use_part);
  reduce_kernel<<<dim3(256), dim3(256), 0, stream>>>(colpart,
                                                     rowmax_u, colmax_u, y2h,
                                                     out, use_part);
}

// Round 10
// 157.855 us; speedup vs baseline: 1.0056x; 1.0056x over previous
//
#include <hip/hip_runtime.h>
#include <cstdint>
#include <cstddef>

typedef unsigned short u16;
typedef __attribute__((ext_vector_type(8))) short short8;
typedef __attribute__((ext_vector_type(8))) u16 ushort8;
typedef __attribute__((ext_vector_type(4))) float float4_t;

#define BB 8
#define NN 8192
#define DD 64
#define TILE_SHORTS 8192     // 128 points * 64 k (bf16)
#define LDS_STRIDE 68        // 64 floats + 4 pad (bank spread)

__device__ inline u16 f32_to_bf16(float f) {
  unsigned u = __float_as_uint(f);
  u += 0x7FFFu + ((u >> 16) & 1u);   // RNE
  return (u16)(u >> 16);
}

__device__ inline unsigned enc_ord(float f) {
  unsigned u = __float_as_uint(f);
  return (u & 0x80000000u) ? ~u : (u | 0x80000000u);
}
__device__ inline float dec_ord(unsigned u) {
  return __uint_as_float((u & 0x80000000u) ? (u & 0x7fffffffu) : ~u);
}

// ---------------------------------------------------------------------------
// K1: one block = one 128x64 tile. Coalesced read-once -> LDS -> swizzled
// bf16 tile (MFMA fragment chunk order) + 0.5*|row|^2.  [verified R6/R7]
// rowmax_u zero-inited ALWAYS (rows use end-of-kernel atomics both paths);
// colmax_u only in the fallback path.
// ---------------------------------------------------------------------------
__global__ __launch_bounds__(256) void pre_kernel(
    const float* __restrict__ x, const float* __restrict__ y,
    u16* __restrict__ xs, u16* __restrict__ ys,
    float* __restrict__ x2h, float* __restrict__ y2h,
    unsigned* __restrict__ rowmax_u, unsigned* __restrict__ colmax_u,
    float* __restrict__ out, const int use_part)
{
  __shared__ float stage[128 * LDS_STRIDE];   // 34 KB

  const int bid = blockIdx.x;          // 1024: 0..511 -> x, 512..1023 -> y
  const int tid = threadIdx.x;

  if (bid >= 256 && bid < 512) rowmax_u[((bid - 256) << 8) | tid] = 0u;
  if (!use_part && bid < 256)  colmax_u[(bid << 8) | tid] = 0u;
  if (bid == 0 && tid == 0) out[0] = 0.f;

  const bool isY = bid >= 512;
  const int t = bid & 511;             // tile id = b*64 + nt
  const float* src = (isY ? y : x) + (size_t)t * (128 * DD);
  u16* dst = (isY ? ys : xs) + (size_t)t * TILE_SHORTS;
  float* s2 = (isY ? y2h : x2h) + t * 128;

#pragma unroll
  for (int c = 0; c < 8; ++c) {
    const int idx = c * 256 + tid;     // float4 index within tile (0..2047)
    float4 f = ((const float4*)src)[idx];
    const int r = idx >> 4, kc = idx & 15;
    *(float4*)&stage[r * LDS_STRIDE + kc * 4] = f;
  }
  __syncthreads();

  {
    const int r = tid >> 1, half = tid & 1;
    const float* rp = &stage[r * LDS_STRIDE + half * 32];
    float ss = 0.f;
#pragma unroll
    for (int k = 0; k < 8; ++k) {
      float4 f = *(const float4*)&rp[k * 4];
      ss += f.x*f.x + f.y*f.y + f.z*f.z + f.w*f.w;
    }
    ss += __shfl_xor(ss, 1);
    if (half == 0) s2[r] = 0.5f * ss;
  }

  {
    const int w = tid >> 6, lane = tid & 63;
    const int qq = lane >> 4, rl = lane & 15;
#pragma unroll
    for (int u = 0; u < 4; ++u) {
      const int chunk = w * 4 + u;
      const int I = chunk >> 1, s = chunk & 1;
      const float* rp = &stage[(I*16 + rl) * LDS_STRIDE + s*32 + qq*8];
      ushort8 o;
#pragma unroll
      for (int j = 0; j < 8; ++j) o[j] = f32_to_bf16(rp[j]);
      *(ushort8*)(dst + chunk*512 + lane*8) = o;
    }
  }
}

// ---------------------------------------------------------------------------
// K2: main — R18.  R17 post-mortem: delayed-reduce was ~neutral (41.3 vs
// 39.6 MfmaUtil) -> acc-writeback wasn't the serializer; compiler already
// interleaved reduce under MFMA. Remaining ~500 cyc/step all-waves stall.
// KEY LEDGER FACT: prefetch depth NEVER mattered (R11 none=105, R12
// depth-1=100, R14 depth-2=100) — the signature of the scheduler SINKING
// prefetch loads to just before use (hipcc preserves no source distance),
// so every step pays a full L2 round trip (~200-300 cyc) x2 wait points
// (B-frags, y2) ~= the hole.
// R18 = R17 + ONE __builtin_amdgcn_sched_barrier(0) per step, placed
// between the prefetch loads and the MFMA cluster: loads are pinned to
// issue BEFORE the step's compute; consumption is 2 steps (~2000 cyc)
// later -> auto-waitcnt becomes a no-op. This is a single pin per step
// (64 total), NOT the m141 pin-everything failure mode; all other code in
// the step stays freely schedulable. Zero math/register change.
// If neutral: loads were already early -> next lever is 32x32x16 MFMA
// shape (+17% MFMA-pipe efficiency, half the MFMA instructions).
// (256,4) ban stands. Tripwires: VGPR ~80, WRITE 17.4 MB.
// ---------------------------------------------------------------------------
__global__ __launch_bounds__(256, 3) void main_kernel(
    const u16* __restrict__ xs, const u16* __restrict__ ys,
    const float* __restrict__ x2h, const float* __restrict__ y2h,
    float* __restrict__ colpart,
    unsigned* __restrict__ rowmax_u, unsigned* __restrict__ colmax_u,
    const int use_part)
{
  __shared__ unsigned colbufu[2048];   // 8 KB: [mt*128 + col], enc_ord
  __shared__ float rowbuf[2][128];     // [wc][row]

  const int bid = blockIdx.x;            // 2048
  const int b   = bid & 7;               // XCD-affine
  const int nt  = (bid >> 3) & 63;
  const int h   = bid >> 9;              // 0..3 column quarter
  const int tid = threadIdx.x;
  const int w = tid >> 6, lane = tid & 63;
  const int wr = w >> 1, wc = w & 1;     // row-half / col-half owner
  const int l15 = lane & 15, q = lane >> 4;
  const int n0 = nt << 7;
  const int mt_start = h << 4;           // 16 col-tiles per block

  // colbufu init: 0u is below enc_ord of every finite float
#pragma unroll
  for (int k = 0; k < 8; ++k) colbufu[k * 256 + tid] = 0u;

  // ---- A fragments: this wave's 64 rows, both K-halves ----
  const u16* xs_tile = xs + (size_t)((b << 6) | nt) * TILE_SHORTS;
  short8 afr[4][2];
#pragma unroll
  for (int i = 0; i < 4; ++i)
#pragma unroll
    for (int s = 0; s < 2; ++s)
      afr[i][s] = *(const short8*)(xs_tile + ((wr*4 + i)*2 + s)*512 + lane*8);

  // ---- C-init quads: -x2/2 per row (fp32 exact) ----
  float4_t negx2[4];
  const float* x2b = x2h + b*NN + n0 + wr*64;
#pragma unroll
  for (int i = 0; i < 4; ++i) {
    float4_t v = *(const float4_t*)(x2b + i*16 + q*4);
    negx2[i] = {-v[0], -v[1], -v[2], -v[3]};
  }

  float rowmax[4][4];
#pragma unroll
  for (int i = 0; i < 4; ++i)
#pragma unroll
    for (int r = 0; r < 4; ++r) rowmax[i][r] = -3.0e38f;

  // ---- pointer-bumped streams; imm offsets cover the chunk loads ----
  const u16*  pB = ys + (size_t)((b << 6) + mt_start) * TILE_SHORTS
                   + wc*4096 + lane*8;
  const float* pY = y2h + b*NN + mt_start*128 + wc*64 + l15;

  // ---- depth-2 pipeline, 4 static B buffers + acc ping-pong ----
  short8 b0lo, b0hi, b1lo, b1hi, b2lo, b2hi, b3lo, b3hi;
  float  y20, y21, y22, y23;
  b0lo = *(const short8*)(pB);
  b0hi = *(const short8*)(pB + 512);
  y20  = pY[0];
  b1lo = *(const short8*)(pB + 1024);
  b1hi = *(const short8*)(pB + 1536);
  y21  = pY[16];
  y23  = 0.f;                            // dummy first reduce reads it

  float4_t accA[4], accB[4];
#pragma unroll
  for (int i = 0; i < 4; ++i)
    accB[i] = {-3.0e38f, -3.0e38f, -3.0e38f, -3.0e38f};  // dummy: no-op reduce

  __syncthreads();                       // colbufu init visible to all waves

  int moff = 0;
  for (int mt = 0; mt < 16; ++mt) {
    const int mprev = (moff == 0) ? 0 : (moff - 128);
    // STEP(JJ): prefetch step JJ+2 (pinned early by sched_barrier); MFMA
    // step JJ into AC; reduce PREVIOUS step's acc AP (independent of the
    // in-flight MFMAs).
#define CHAM_STEP(JJ, NOFF, NY, C0, C1, YC, N0, N1, YN, AC, AP, PJJ, PYC, PMOFF) \
    {                                                                         \
      N0 = *(const short8*)(pB + (NOFF));                                     \
      N1 = *(const short8*)(pB + (NOFF) + 512);                               \
      YN = pY[(NY)];                                                          \
      __builtin_amdgcn_sched_barrier(0);  /* pin loads BEFORE compute */      \
      /* acc = xy - x2/2 (C carries exact fp32 -x2/2) */                      \
      __builtin_amdgcn_s_setprio(1);                                          \
      AC[0] = __builtin_amdgcn_mfma_f32_16x16x32_bf16(afr[0][0], C0, negx2[0], 0, 0, 0); \
      AC[1] = __builtin_amdgcn_mfma_f32_16x16x32_bf16(afr[1][0], C0, negx2[1], 0, 0, 0); \
      AC[2] = __builtin_amdgcn_mfma_f32_16x16x32_bf16(afr[2][0], C0, negx2[2], 0, 0, 0); \
      AC[3] = __builtin_amdgcn_mfma_f32_16x16x32_bf16(afr[3][0], C0, negx2[3], 0, 0, 0); \
      AC[0] = __builtin_amdgcn_mfma_f32_16x16x32_bf16(afr[0][1], C1, AC[0], 0, 0, 0);    \
      AC[1] = __builtin_amdgcn_mfma_f32_16x16x32_bf16(afr[1][1], C1, AC[1], 0, 0, 0);    \
      AC[2] = __builtin_amdgcn_mfma_f32_16x16x32_bf16(afr[2][1], C1, AC[2], 0, 0, 0);    \
      AC[3] = __builtin_amdgcn_mfma_f32_16x16x32_bf16(afr[3][1], C1, AC[3], 0, 0, 0);    \
      __builtin_amdgcn_s_setprio(0);                                          \
      /* reduce previous acc: in-lane 16-row max tree + fire-and-forget    */ \
      /* LDS ds_max_u32 (result unused -> no wave-visible wait)            */ \
      float t0 = fmaxf(fmaxf(AP[0][0], AP[0][1]), AP[0][2]);                  \
      float t1 = fmaxf(fmaxf(AP[0][3], AP[1][0]), AP[1][1]);                  \
      float t2 = fmaxf(fmaxf(AP[1][2], AP[1][3]), AP[2][0]);                  \
      float t3 = fmaxf(fmaxf(AP[2][1], AP[2][2]), AP[2][3]);                  \
      float t4 = fmaxf(fmaxf(AP[3][0], AP[3][1]), AP[3][2]);                  \
      float u0 = fmaxf(fmaxf(t0, t1), t2);                                    \
      float u1 = fmaxf(fmaxf(t3, t4), AP[3][3]);                              \
      float cm = fmaxf(u0, u1);                                               \
      atomicMax(&colbufu[(PMOFF) + wc*64 + (PJJ)*16 + l15], enc_ord(cm));     \
      /* row side: rowmax = max(AP - y2/2) = -min(d^2)/2 */                   \
      {                                                                       \
        const float y2j = (PYC);                                              \
        for (int i_ = 0; i_ < 4; ++i_)                                        \
          for (int r_ = 0; r_ < 4; ++r_)                                      \
            rowmax[i_][r_] = fmaxf(rowmax[i_][r_], AP[i_][r_] - y2j);         \
      }                                                                       \
    }
    // step jj: consume b[jj], load b[(jj+2)&3]; reduce step jj-1's acc
    CHAM_STEP(0, 2048,              32,  b0lo, b0hi, y20, b2lo, b2hi, y22,
              accA, accB, 3, y23, mprev)
    CHAM_STEP(1, 3072,              48,  b1lo, b1hi, y21, b3lo, b3hi, y23,
              accB, accA, 0, y20, moff)
    CHAM_STEP(2, TILE_SHORTS,       128, b2lo, b2hi, y22, b0lo, b0hi, y20,
              accA, accB, 1, y21, moff)
    CHAM_STEP(3, TILE_SHORTS+1024,  144, b3lo, b3hi, y23, b1lo, b1hi, y21,
              accB, accA, 2, y22, moff)
#undef CHAM_STEP
    pB += TILE_SHORTS;
    pY += 128;
    moff += 128;
  }

  // ---- epilogue: reduce the final step's acc (mt15, jj3, y23 live) ----
  {
    const int pmoff = moff - 128;        // 1920
    float t0 = fmaxf(fmaxf(accB[0][0], accB[0][1]), accB[0][2]);
    float t1 = fmaxf(fmaxf(accB[0][3], accB[1][0]), accB[1][1]);
    float t2 = fmaxf(fmaxf(accB[1][2], accB[1][3]), accB[2][0]);
    float t3 = fmaxf(fmaxf(accB[2][1], accB[2][2]), accB[2][3]);
    float t4 = fmaxf(fmaxf(accB[3][0], accB[3][1]), accB[3][2]);
    float u0 = fmaxf(fmaxf(t0, t1), t2);
    float u1 = fmaxf(fmaxf(t3, t4), accB[3][3]);
    float cm = fmaxf(u0, u1);
    atomicMax(&colbufu[pmoff + wc*64 + 3*16 + l15], enc_ord(cm));
    const float y2j = y23;
#pragma unroll
    for (int i_ = 0; i_ < 4; ++i_)
#pragma unroll
      for (int r_ = 0; r_ < 4; ++r_)
        rowmax[i_][r_] = fmaxf(rowmax[i_][r_], accB[i_][r_] - y2j);
  }

  // ---- row side finalize: shfl over cols (l15), cross-wc via LDS ----
#pragma unroll
  for (int i = 0; i < 4; ++i)
#pragma unroll
    for (int r = 0; r < 4; ++r) {
      float v = rowmax[i][r];
      v = fmaxf(v, __shfl_xor(v, 1));
      v = fmaxf(v, __shfl_xor(v, 2));
      v = fmaxf(v, __shfl_xor(v, 4));
      v = fmaxf(v, __shfl_xor(v, 8));
      rowmax[i][r] = v;
    }
  if (l15 == 0) {
#pragma unroll
    for (int i = 0; i < 4; ++i)
#pragma unroll
      for (int r = 0; r < 4; ++r)
        rowbuf[wc][wr*64 + i*16 + q*4 + r] = rowmax[i][r];
  }
  __syncthreads();   // colbufu atomics + rowbuf complete (lgkmcnt-drained)

  // rows: one end-of-kernel device atomic per row (both paths)
  if (tid < 128) {
    float v = fmaxf(rowbuf[0][tid], rowbuf[1][tid]);     // -min(d^2)/2
    atomicMax(&rowmax_u[b*NN + n0 + tid], enc_ord(v));
  }

  // ---- col drain: decode single plane; 8 KB coalesced (partial path) ----
  {
    float*    colp = colpart + (size_t)((b << 6) | nt) * NN + (h << 11);
    unsigned* colu = colmax_u + b*NN + (h << 11);
#pragma unroll
    for (int k = 0; k < 8; ++k) {
      const int t = k * 256 + tid;
      const unsigned e = colbufu[t];
      if (use_part) colp[t] = dec_ord(e);
      else          atomicMax(&colu[t], e);
    }
  }
}

// ---------------------------------------------------------------------------
// K3: col combine over 64 nt + sqrt; rows from rowmax_u (always atomic) +
// sqrt; block sum; atomicAdd scaled result into out.
// ---------------------------------------------------------------------------
__global__ __launch_bounds__(256) void reduce_kernel(
    const float* __restrict__ colpart,
    const unsigned* __restrict__ rowmax_u, const unsigned* __restrict__ colmax_u,
    const float* __restrict__ y2h, float* __restrict__ out,
    const int use_part)
{
  const int bid = blockIdx.x;          // 256
  const int tid = threadIdx.x;
  const int g = bid*256 + tid;         // 0..65535
  const int b = g >> 13, m = g & (NN - 1);

  float vc;
  if (use_part) {
    vc = -3.0e38f;
#pragma unroll 8
    for (int nt = 0; nt < 64; ++nt)
      vc = fmaxf(vc, colpart[(size_t)((b << 6) | nt) * NN + m]);
  } else {
    vc = dec_ord(colmax_u[g]);
  }
  float vr = dec_ord(rowmax_u[g]);
  float s = sqrtf(fmaxf(2.f*(y2h[g] - vc), 0.f))   // nearest-x for this y
          + sqrtf(fmaxf(-2.f*vr, 0.f));            // nearest-y for this x

#pragma unroll
  for (int d = 1; d < 64; d <<= 1) s += __shfl_xor(s, d);
  __shared__ float wsum[4];
  if ((tid & 63) == 0) wsum[tid >> 6] = s;
  __syncthreads();
  if (tid == 0)
    atomicAdd(out, (wsum[0] + wsum[1] + wsum[2] + wsum[3]) * (1.0f / 65536.0f));
}

// ---------------------------------------------------------------------------
extern "C" void kernel_launch(void* const* d_in, const int* in_sizes, int n_in,
                              void* d_out, int out_size, void* d_ws, size_t ws_size,
                              hipStream_t stream) {
  const float* x = (const float*)d_in[0];
  const float* y = (const float*)d_in[1];
  float* out = (float*)d_out;

  char* p = (char*)d_ws;
  u16* xs = (u16*)p;            p += (size_t)512 * 16384;   // 8 MiB
  u16* ys = (u16*)p;            p += (size_t)512 * 16384;   // 8 MiB
  float* x2h = (float*)p;       p += (size_t)65536 * 4;
  float* y2h = (float*)p;       p += (size_t)65536 * 4;
  char* tail = p;
  // partial path: colpart 16 MiB, then rowmax_u 256 KiB.
  // need = 16.5 + 16 + 0.25 = 32.75 MiB  (< R0-proven 33.0 MiB)
  float* colpart = (float*)tail;
  // atomic fallback: colmax_u at tail, rowmax_u right after (512 KiB total)
  unsigned* colmax_u = (unsigned*)tail;
  const size_t need_part = (size_t)(tail - (char*)d_ws) +
                           (size_t)512 * 8192 * 4 + (size_t)65536 * 4;
  const int use_part = (ws_size >= need_part) ? 1 : 0;
  unsigned* rowmax_u = use_part
      ? (unsigned*)(tail + (size_t)512 * 8192 * 4)
      : (unsigned*)(tail + (size_t)65536 * 4);

  pre_kernel<<<dim3(1024), dim3(256), 0, stream>>>(x, y, xs, ys, x2h, y2h,
                                                   rowmax_u, colmax_u, out,
                                                   use_part);
  main_kernel<<<dim3(2048), dim3(256), 0, stream>>>(xs, ys, x2h, y2h,
                                                    colpart,
                                                    rowmax_u, colmax_u,
                                                    use_part);
  reduce_kernel<<<dim3(256), dim3(256), 0, stream>>>(colpart,
                                                     rowmax_u, colmax_u, y2h,
                                                     out, use_part);
}